// Round 2
// baseline (170.808 us; speedup 1.0000x reference)
//
#include <hip/hip_runtime.h>

// All tensors are float32 (reference declares jnp.float32; harness maps
// float32 -> const float*). Output = concat(vec[3E], dist[E], switch[E],
// mask_as_float[E]).
//
// Numerics: the edge_mask (d < 5.0) is a binary cliff — we must match the
// numpy f32 reference bit-for-bit on d. So: fp contract OFF (no fma), exact
// numpy op order: vec = (cd - cs) + ((s0*c0j + s1*c1j) + s2*c2j),
// q = (v0^2 + v1^2) + v2^2, d = sqrtf(q) (correctly rounded OCML).
// switch uses accurate cosf (we're memory-bound; VALU is free).

__device__ __forceinline__ void edge_compute(
    const float* __restrict__ coords, int s, int d,
    float sh0, float sh1, float sh2, const float c[9],
    float& v0, float& v1, float& v2, float& dist, float& sw, float& mk)
{
#pragma clang fp contract(off)
    const float* cs = coords + 3 * (size_t)s;
    const float* cd = coords + 3 * (size_t)d;
    float x0 = cd[0] - cs[0];
    float x1 = cd[1] - cs[1];
    float x2 = cd[2] - cs[2];
    // (shifts @ cells)[j], numpy sequential dot order, no fma
    float m0 = sh0 * c[0]; m0 = m0 + sh1 * c[3]; m0 = m0 + sh2 * c[6];
    float m1 = sh0 * c[1]; m1 = m1 + sh1 * c[4]; m1 = m1 + sh2 * c[7];
    float m2 = sh0 * c[2]; m2 = m2 + sh1 * c[5]; m2 = m2 + sh2 * c[8];
    v0 = x0 + m0; v1 = x1 + m1; v2 = x2 + m2;
    float q = v0 * v0; q = q + v1 * v1; q = q + v2 * v2;
    dist = sqrtf(q);
    bool m = dist < 5.0f;
    float cv = cosf(dist * 0.62831853f);   // f32(pi/5)
    sw = m ? (0.5f * cv + 0.5f) : 0.0f;
    mk = m ? 1.0f : 0.0f;
}

__global__ __launch_bounds__(256) void GraphProcessor_64012192579962_kernel(
    const float* __restrict__ coords,   // [N,3]
    const int*   __restrict__ esrc,     // [E]
    const int*   __restrict__ edst,     // [E]
    const float* __restrict__ shifts,   // [E,3]
    const float* __restrict__ cells,    // [9]
    float* __restrict__ out_vec,        // [E,3]
    float* __restrict__ out_dist,       // [E]
    float* __restrict__ out_sw,         // [E]
    float* __restrict__ out_mask,       // [E]
    int n_quads, int n_edges)
{
#pragma clang fp contract(off)
    int t = blockIdx.x * blockDim.x + threadIdx.x;
    if (t >= n_quads) return;

    float c[9];
#pragma unroll
    for (int i = 0; i < 9; ++i) c[i] = cells[i];   // uniform -> scalar loads

    const int e0 = 4 * t;

    if (e0 + 3 < n_edges) {
        // fast path: 4 edges, all stream accesses are 16B dwordx4
        int4 ss = ((const int4*)esrc)[t];
        int4 dd = ((const int4*)edst)[t];
        const float4* shp = (const float4*)(shifts + 12 * (size_t)t);
        float4 h0 = shp[0], h1 = shp[1], h2 = shp[2];

        float v[12], di[4], sw[4], mk[4];
        edge_compute(coords, ss.x, dd.x, h0.x, h0.y, h0.z, c, v[0], v[1],  v[2],  di[0], sw[0], mk[0]);
        edge_compute(coords, ss.y, dd.y, h0.w, h1.x, h1.y, c, v[3], v[4],  v[5],  di[1], sw[1], mk[1]);
        edge_compute(coords, ss.z, dd.z, h1.z, h1.w, h2.x, c, v[6], v[7],  v[8],  di[2], sw[2], mk[2]);
        edge_compute(coords, ss.w, dd.w, h2.y, h2.z, h2.w, c, v[9], v[10], v[11], di[3], sw[3], mk[3]);

        float4* ov = (float4*)(out_vec + 12 * (size_t)t);
        ov[0] = make_float4(v[0], v[1], v[2],  v[3]);
        ov[1] = make_float4(v[4], v[5], v[6],  v[7]);
        ov[2] = make_float4(v[8], v[9], v[10], v[11]);
        ((float4*)out_dist)[t] = make_float4(di[0], di[1], di[2], di[3]);
        ((float4*)out_sw)[t]   = make_float4(sw[0], sw[1], sw[2], sw[3]);
        ((float4*)out_mask)[t] = make_float4(mk[0], mk[1], mk[2], mk[3]);
    } else {
        for (int e = e0; e < n_edges; ++e) {
            float v0, v1, v2, di, sw, mk;
            edge_compute(coords, esrc[e], edst[e],
                         shifts[3 * (size_t)e], shifts[3 * (size_t)e + 1],
                         shifts[3 * (size_t)e + 2], c, v0, v1, v2, di, sw, mk);
            out_vec[3 * (size_t)e]     = v0;
            out_vec[3 * (size_t)e + 1] = v1;
            out_vec[3 * (size_t)e + 2] = v2;
            out_dist[e] = di;
            out_sw[e]   = sw;
            out_mask[e] = mk;
        }
    }
}

extern "C" void kernel_launch(void* const* d_in, const int* in_sizes, int n_in,
                              void* d_out, int out_size, void* d_ws, size_t ws_size,
                              hipStream_t stream) {
    const float* coords = (const float*)d_in[0];
    const int*   esrc   = (const int*)d_in[1];
    const int*   edst   = (const int*)d_in[2];
    const float* shifts = (const float*)d_in[3];
    const float* cells  = (const float*)d_in[4];

    const int E = in_sizes[1];  // n_edges

    float* out      = (float*)d_out;
    float* out_vec  = out;                     // [E,3]
    float* out_dist = out + 3 * (size_t)E;     // [E]
    float* out_sw   = out_dist + E;            // [E]
    float* out_mask = out_sw + E;              // [E]

    const int n_quads = (E + 3) / 4;
    dim3 block(256);
    dim3 grid((n_quads + 255) / 256);
    GraphProcessor_64012192579962_kernel<<<grid, block, 0, stream>>>(
        coords, esrc, edst, shifts, cells,
        out_vec, out_dist, out_sw, out_mask, n_quads, E);
}

// Round 3
// 169.928 us; speedup vs baseline: 1.0052x; 1.0052x over previous
//
#include <hip/hip_runtime.h>

// All tensors float32. Output = concat(vec[3E], dist[E], switch[E], mask[E]).
//
// R1 post-mortem: 71us, HBM 20%, VALU 8% -> bound by divergent-gather lane
// throughput (6 scalar dword gathers/edge, 12B payload straddling lines).
// R2: pack coords into float4[N] in d_ws (prepass) so each node gather is a
// single 16B-aligned dwordx4 (one line, one instr). 3x fewer gather instrs,
// zero line splits. Value arithmetic unchanged (must stay bit-exact: the
// d<5 mask is a cliff; fp contract OFF, numpy op order, OCML sqrtf).

__device__ __forceinline__ void edge_math(
    float dx0, float dx1, float dx2,
    float sh0, float sh1, float sh2, const float c[9],
    float& v0, float& v1, float& v2, float& dist, float& sw, float& mk)
{
#pragma clang fp contract(off)
    float m0 = sh0 * c[0]; m0 = m0 + sh1 * c[3]; m0 = m0 + sh2 * c[6];
    float m1 = sh0 * c[1]; m1 = m1 + sh1 * c[4]; m1 = m1 + sh2 * c[7];
    float m2 = sh0 * c[2]; m2 = m2 + sh1 * c[5]; m2 = m2 + sh2 * c[8];
    v0 = dx0 + m0; v1 = dx1 + m1; v2 = dx2 + m2;
    float q = v0 * v0; q = q + v1 * v1; q = q + v2 * v2;
    dist = sqrtf(q);
    bool m = dist < 5.0f;
    float cv = cosf(dist * 0.62831853f);   // f32(pi/5)
    sw = m ? (0.5f * cv + 0.5f) : 0.0f;
    mk = m ? 1.0f : 0.0f;
}

// ---- prepass: coords[N,3] -> packed float4[N] in ws ----
__global__ __launch_bounds__(256) void pack_coords_kernel(
    const float* __restrict__ coords, float4* __restrict__ packed, int n_nodes)
{
    int i = blockIdx.x * blockDim.x + threadIdx.x;
    if (i >= n_nodes) return;
    const float* p = coords + 3 * (size_t)i;
    packed[i] = make_float4(p[0], p[1], p[2], 0.0f);
}

// ---- main kernel, packed-float4 gather path ----
__global__ __launch_bounds__(256) void GraphProcessor_64012192579962_kernel(
    const float4* __restrict__ packed,  // [N] xyz_
    const int*   __restrict__ esrc,     // [E]
    const int*   __restrict__ edst,     // [E]
    const float* __restrict__ shifts,   // [E,3]
    const float* __restrict__ cells,    // [9]
    float* __restrict__ out_vec,        // [E,3]
    float* __restrict__ out_dist,       // [E]
    float* __restrict__ out_sw,         // [E]
    float* __restrict__ out_mask,       // [E]
    int n_quads, int n_edges)
{
#pragma clang fp contract(off)
    int t = blockIdx.x * blockDim.x + threadIdx.x;
    if (t >= n_quads) return;

    float c[9];
#pragma unroll
    for (int i = 0; i < 9; ++i) c[i] = cells[i];   // uniform -> scalar loads

    const int e0 = 4 * t;

    if (e0 + 3 < n_edges) {
        int4 ss = ((const int4*)esrc)[t];
        int4 dd = ((const int4*)edst)[t];
        const float4* shp = (const float4*)(shifts + 12 * (size_t)t);
        float4 h0 = shp[0], h1 = shp[1], h2 = shp[2];

        // issue all 8 gathers before any compute (max outstanding loads)
        float4 s0 = packed[ss.x], s1 = packed[ss.y], s2 = packed[ss.z], s3 = packed[ss.w];
        float4 d0 = packed[dd.x], d1 = packed[dd.y], d2 = packed[dd.z], d3 = packed[dd.w];

        float v[12], di[4], sw[4], mk[4];
        edge_math(d0.x - s0.x, d0.y - s0.y, d0.z - s0.z, h0.x, h0.y, h0.z, c, v[0], v[1],  v[2],  di[0], sw[0], mk[0]);
        edge_math(d1.x - s1.x, d1.y - s1.y, d1.z - s1.z, h0.w, h1.x, h1.y, c, v[3], v[4],  v[5],  di[1], sw[1], mk[1]);
        edge_math(d2.x - s2.x, d2.y - s2.y, d2.z - s2.z, h1.z, h1.w, h2.x, c, v[6], v[7],  v[8],  di[2], sw[2], mk[2]);
        edge_math(d3.x - s3.x, d3.y - s3.y, d3.z - s3.z, h2.y, h2.z, h2.w, c, v[9], v[10], v[11], di[3], sw[3], mk[3]);

        float4* ov = (float4*)(out_vec + 12 * (size_t)t);
        ov[0] = make_float4(v[0], v[1], v[2],  v[3]);
        ov[1] = make_float4(v[4], v[5], v[6],  v[7]);
        ov[2] = make_float4(v[8], v[9], v[10], v[11]);
        ((float4*)out_dist)[t] = make_float4(di[0], di[1], di[2], di[3]);
        ((float4*)out_sw)[t]   = make_float4(sw[0], sw[1], sw[2], sw[3]);
        ((float4*)out_mask)[t] = make_float4(mk[0], mk[1], mk[2], mk[3]);
    } else {
        for (int e = e0; e < n_edges; ++e) {
            float4 s = packed[esrc[e]], d = packed[edst[e]];
            float v0, v1, v2, di, sw, mk;
            edge_math(d.x - s.x, d.y - s.y, d.z - s.z,
                      shifts[3 * (size_t)e], shifts[3 * (size_t)e + 1],
                      shifts[3 * (size_t)e + 2], c, v0, v1, v2, di, sw, mk);
            out_vec[3 * (size_t)e]     = v0;
            out_vec[3 * (size_t)e + 1] = v1;
            out_vec[3 * (size_t)e + 2] = v2;
            out_dist[e] = di;
            out_sw[e]   = sw;
            out_mask[e] = mk;
        }
    }
}

// ---- fallback (ws too small): 12B struct gathers straight from coords ----
struct F3 { float x, y, z; };

__global__ __launch_bounds__(256) void GraphProcessor_fallback_kernel(
    const float* __restrict__ coords,
    const int*   __restrict__ esrc,
    const int*   __restrict__ edst,
    const float* __restrict__ shifts,
    const float* __restrict__ cells,
    float* __restrict__ out_vec,
    float* __restrict__ out_dist,
    float* __restrict__ out_sw,
    float* __restrict__ out_mask,
    int n_quads, int n_edges)
{
#pragma clang fp contract(off)
    int t = blockIdx.x * blockDim.x + threadIdx.x;
    if (t >= n_quads) return;

    float c[9];
#pragma unroll
    for (int i = 0; i < 9; ++i) c[i] = cells[i];

    const F3* nodes = (const F3*)coords;
    const int e0 = 4 * t;

    if (e0 + 3 < n_edges) {
        int4 ss = ((const int4*)esrc)[t];
        int4 dd = ((const int4*)edst)[t];
        const float4* shp = (const float4*)(shifts + 12 * (size_t)t);
        float4 h0 = shp[0], h1 = shp[1], h2 = shp[2];

        F3 s0 = nodes[ss.x], s1 = nodes[ss.y], s2 = nodes[ss.z], s3 = nodes[ss.w];
        F3 d0 = nodes[dd.x], d1 = nodes[dd.y], d2 = nodes[dd.z], d3 = nodes[dd.w];

        float v[12], di[4], sw[4], mk[4];
        edge_math(d0.x - s0.x, d0.y - s0.y, d0.z - s0.z, h0.x, h0.y, h0.z, c, v[0], v[1],  v[2],  di[0], sw[0], mk[0]);
        edge_math(d1.x - s1.x, d1.y - s1.y, d1.z - s1.z, h0.w, h1.x, h1.y, c, v[3], v[4],  v[5],  di[1], sw[1], mk[1]);
        edge_math(d2.x - s2.x, d2.y - s2.y, d2.z - s2.z, h1.z, h1.w, h2.x, c, v[6], v[7],  v[8],  di[2], sw[2], mk[2]);
        edge_math(d3.x - s3.x, d3.y - s3.y, d3.z - s3.z, h2.y, h2.z, h2.w, c, v[9], v[10], v[11], di[3], sw[3], mk[3]);

        float4* ov = (float4*)(out_vec + 12 * (size_t)t);
        ov[0] = make_float4(v[0], v[1], v[2],  v[3]);
        ov[1] = make_float4(v[4], v[5], v[6],  v[7]);
        ov[2] = make_float4(v[8], v[9], v[10], v[11]);
        ((float4*)out_dist)[t] = make_float4(di[0], di[1], di[2], di[3]);
        ((float4*)out_sw)[t]   = make_float4(sw[0], sw[1], sw[2], sw[3]);
        ((float4*)out_mask)[t] = make_float4(mk[0], mk[1], mk[2], mk[3]);
    } else {
        for (int e = e0; e < n_edges; ++e) {
            F3 s = nodes[esrc[e]], d = nodes[edst[e]];
            float v0, v1, v2, di, sw, mk;
            edge_math(d.x - s.x, d.y - s.y, d.z - s.z,
                      shifts[3 * (size_t)e], shifts[3 * (size_t)e + 1],
                      shifts[3 * (size_t)e + 2], c, v0, v1, v2, di, sw, mk);
            out_vec[3 * (size_t)e]     = v0;
            out_vec[3 * (size_t)e + 1] = v1;
            out_vec[3 * (size_t)e + 2] = v2;
            out_dist[e] = di;
            out_sw[e]   = sw;
            out_mask[e] = mk;
        }
    }
}

extern "C" void kernel_launch(void* const* d_in, const int* in_sizes, int n_in,
                              void* d_out, int out_size, void* d_ws, size_t ws_size,
                              hipStream_t stream) {
    const float* coords = (const float*)d_in[0];
    const int*   esrc   = (const int*)d_in[1];
    const int*   edst   = (const int*)d_in[2];
    const float* shifts = (const float*)d_in[3];
    const float* cells  = (const float*)d_in[4];

    const int N = in_sizes[0] / 3;  // n_nodes
    const int E = in_sizes[1];      // n_edges

    float* out      = (float*)d_out;
    float* out_vec  = out;                     // [E,3]
    float* out_dist = out + 3 * (size_t)E;     // [E]
    float* out_sw   = out_dist + E;            // [E]
    float* out_mask = out_sw + E;              // [E]

    const int n_quads = (E + 3) / 4;
    dim3 block(256);
    dim3 grid((n_quads + 255) / 256);

    if (ws_size >= (size_t)N * sizeof(float4)) {
        float4* packed = (float4*)d_ws;
        pack_coords_kernel<<<(N + 255) / 256, 256, 0, stream>>>(coords, packed, N);
        GraphProcessor_64012192579962_kernel<<<grid, block, 0, stream>>>(
            packed, esrc, edst, shifts, cells,
            out_vec, out_dist, out_sw, out_mask, n_quads, E);
    } else {
        GraphProcessor_fallback_kernel<<<grid, block, 0, stream>>>(
            coords, esrc, edst, shifts, cells,
            out_vec, out_dist, out_sw, out_mask, n_quads, E);
    }
}